// Round 12
// baseline (738.776 us; speedup 1.0000x reference)
//
#include <hip/hip_runtime.h>

typedef unsigned int u32;
typedef unsigned short u16;
typedef unsigned long long u64;

#define B_ 2048
#define A_ 4096
#define D_ 32768
#define K_ 4096
#define CAP0 4194304   // raw candidates (v >= 2.0), expect ~1.5M
#define CAP  131072    // filtered candidates (v >= tau), expect ~12K
#define STASH 1024
#define S_X 28.0f
#define S_W 1792.0f
#define INV_S (1.0f / (28.0f * 1792.0f))
#define MARGIN 0.28f
#define ROWCAP 64

using f32x4 = __attribute__((ext_vector_type(4))) float;
using i32x4 = __attribute__((ext_vector_type(4))) int;

typedef const u32 __attribute__((address_space(1)))* gas_ptr;
typedef u32 __attribute__((address_space(3)))* las_ptr;

__device__ __forceinline__ void load16(const void* g, void* l) {
  __builtin_amdgcn_global_load_lds((gas_ptr)g, (las_ptr)l, 16, 0, 0);
}

__device__ __forceinline__ u32 q8x4(float4 v, float s) {
  int q0 = __float2int_rn(v.x * s); q0 = q0 < -127 ? -127 : (q0 > 127 ? 127 : q0);
  int q1 = __float2int_rn(v.y * s); q1 = q1 < -127 ? -127 : (q1 > 127 ? 127 : q1);
  int q2 = __float2int_rn(v.z * s); q2 = q2 < -127 ? -127 : (q2 > 127 ? 127 : q2);
  int q3 = __float2int_rn(v.w * s); q3 = q3 < -127 ? -127 : (q3 > 127 ? 127 : q3);
  return (u32)(q0 & 0xff) | ((u32)(q1 & 0xff) << 8) | ((u32)(q2 & 0xff) << 16) | ((u32)(q3 & 0xff) << 24);
}

// ---------------- fused prep: quantize W, quantize x-b_dec, zero hist/meta ----------------
__global__ void k_prep(const float* __restrict__ Wf, char* __restrict__ Wq,
                       const float* __restrict__ x, const float* __restrict__ b_dec,
                       char* __restrict__ Xq, u32* __restrict__ gzero) {
  const int bid = blockIdx.x;
  const int t = threadIdx.x;
  if (bid < 32768) {                       // W_enc -> i8 (134.2M elems; block = 4096 elems)
    const long eb = (long)bid * 4096;
#pragma unroll
    for (int p = 0; p < 4; ++p) {
      const long e = eb + p * 1024 + t * 4;
      float4 v = *(const float4*)(Wf + e);
      *(u32*)(Wq + e) = q8x4(v, S_W);
    }
  } else if (bid < 34816) {                // (x - b_dec) -> i8 (8.39M elems)
    const long eb = (long)(bid - 32768) * 4096;
#pragma unroll
    for (int p = 0; p < 4; ++p) {
      const long e = eb + p * 1024 + t * 4;
      const int a0 = (int)(e & (A_ - 1));
      float4 xv = *(const float4*)(x + e);
      float4 bv = *(const float4*)(b_dec + a0);
      float4 d; d.x = xv.x - bv.x; d.y = xv.y - bv.y; d.z = xv.z - bv.z; d.w = xv.w - bv.w;
      *(u32*)(Xq + e) = q8x4(d, S_X);
    }
  } else {                                 // zero ghist(2048) + meta(64) words
    for (int i = t; i < 2112; i += 256) gzero[i] = 0;
  }
}

// ---------------- i8 screening GEMM: 128x128, BK=128, 4 waves, 2 blocks/CU.
// Race-fixed schedule: the cross-wave residency invariant is vmcnt -> BARRIER -> reads.
// Per tile: {barrier; lgkm0; MFMA(b01); barrier; MFMA(b23); vmcnt(0); barrier;
//            ld(t+1); stage(t+2)}. ----------------

#define MFMAQ(NB) \
  __builtin_amdgcn_s_setprio(1); \
  { \
    _Pragma("unroll") \
    for (int m = 0; m < 4; ++m) { \
      _Pragma("unroll") \
      for (int n = 0; n < 2; ++n) { \
        acc[m][NB + n] = __builtin_amdgcn_mfma_i32_16x16x64_i8(a[m][0], b[NB + n][0], acc[m][NB + n], 0, 0, 0); \
        acc[m][NB + n] = __builtin_amdgcn_mfma_i32_16x16x64_i8(a[m][1], b[NB + n][1], acc[m][NB + n], 0, 0, 0); \
      } \
    } \
  } \
  __builtin_amdgcn_s_setprio(0);

__global__ void __launch_bounds__(256, 2)
k_gemm(const char* __restrict__ Xq, const char* __restrict__ Wq,
       const float* __restrict__ b_enc,
       u32* meta_u, u32* __restrict__ ghist,
       u32* __restrict__ c0i, float* __restrict__ c0v) {
  __shared__ __align__(16) char AS[2][128 * 128];   // 16 KiB per buffer
  __shared__ __align__(16) char BS[2][128 * 128];
  __shared__ u32 s_cnt, s_base;
  const int tid = threadIdx.x;
  const int lane = tid & 63, wid = tid >> 6;
  const int wm = wid >> 1, wn = wid & 1;            // 2M x 2N waves, 64x64 out each

  // XCD-aware swizzle: 4096 blocks -> 512-block chunks per XCD, bm fastest (R6-proven)
  const int bid = blockIdx.x;
  const int virt = (bid & 7) * 512 + (bid >> 3);
  const int bm = virt & 15, bn = virt >> 4;
  const long m0 = (long)bm * 128, n0 = (long)bn * 128;

  if (tid == 0) s_cnt = 0;

  // staging: region (64 rows x 128 B = 8 KB) = 2 x load16/thread.
  const int srow = tid >> 3;
  const int sslot = (tid & 7) ^ (srow & 7);         // (h*64, +32) ≡ 0 mod 8 -> invariant
  const char* Abase = Xq + (m0 + srow) * (long)A_ + sslot * 16;
  const char* Bbase = Wq + (n0 + srow) * (long)A_ + sslot * 16;

  auto stageA = [&](int h, int kt) {
    char* dst = &AS[kt & 1][h * 8192] + tid * 16;
    const char* src = Abase + (long)(h * 64) * A_ + kt * 128;
    load16(src, dst);
    load16(src + 32L * A_, dst + 4096);
  };
  auto stageB = [&](int h, int kt) {
    char* dst = &BS[kt & 1][h * 8192] + tid * 16;
    const char* src = Bbase + (long)(h * 64) * A_ + kt * 128;
    load16(src, dst);
    load16(src + 32L * A_, dst + 4096);
  };

  // fragment reads: row R, kslice ks -> byte = R*128 + (((ks<<2)|lh) ^ (R&7))*16
  const int l15 = lane & 15, lh = lane >> 4;
  const int r7 = l15 & 7;
  const int sK0 = (lh ^ r7) * 16;
  const int sK1 = ((4 | lh) ^ r7) * 16;
  const int aBase = (wm * 64 + l15) * 128;
  const int bBase = (wn * 64 + l15) * 128;

  i32x4 acc[4][4] = {};
  i32x4 a[4][2], b[4][2];

  auto ldA = [&](int buf) {
#pragma unroll
    for (int m = 0; m < 4; ++m) {
      a[m][0] = *(const i32x4*)&AS[buf][aBase + m * 2048 + sK0];
      a[m][1] = *(const i32x4*)&AS[buf][aBase + m * 2048 + sK1];
    }
  };
  auto ldB = [&](int buf) {
#pragma unroll
    for (int n = 0; n < 4; ++n) {
      b[n][0] = *(const i32x4*)&BS[buf][bBase + n * 2048 + sK0];
      b[n][1] = *(const i32x4*)&BS[buf][bBase + n * 2048 + sK1];
    }
  };

  // prologue: stage tiles 0 and 1 (8 loads each)
  stageA(0, 0); stageA(1, 0); stageB(0, 0); stageB(1, 0);
  stageA(0, 1); stageA(1, 1); stageB(0, 1); stageB(1, 1);
  asm volatile("s_waitcnt vmcnt(8)" ::: "memory");   // own tile-0 loads done
  __builtin_amdgcn_s_barrier();                      // -> ALL waves' tile-0 loads done
  ldA(0); ldB(0);                                    // safe: reads after the barrier

#pragma unroll 1
  for (int t = 0; t < 32; ++t) {
    const int buf = t & 1;
    // ---- P1: a x b01 (reads issued last iteration, post-vm-barrier) ----
    __builtin_amdgcn_sched_barrier(0);
    __builtin_amdgcn_s_barrier();
    asm volatile("s_waitcnt lgkmcnt(0)" ::: "memory");
    __builtin_amdgcn_sched_barrier(0);
    MFMAQ(0);
    __builtin_amdgcn_sched_barrier(0);
    __builtin_amdgcn_s_barrier();
    // ---- P2: a x b23 ----
    MFMAQ(2);
    __builtin_amdgcn_sched_barrier(0);
    asm volatile("s_waitcnt vmcnt(0)" ::: "memory");  // own stage(t+1) loads done
    __builtin_amdgcn_s_barrier();                     // -> ALL waves' stage(t+1) done
    // ---- post-barrier: issue next reads + next-next stage (both now safe) ----
    // RAW: ld(t+1) happens-after every wave's vmcnt(0)+barrier -> tile t+1 resident.
    // WAR: stage(t+2) writes buf(t); all buf(t) reads retired at each wave's P1-open
    //      lgkmcnt(0), two barriers before this point.
    if (t < 31) { ldA(buf ^ 1); ldB(buf ^ 1); }
    if (t < 30) { stageA(0, t + 2); stageA(1, t + 2); stageB(0, t + 2); stageB(1, t + 2); }
    __builtin_amdgcn_sched_barrier(0);
  }
  __syncthreads();

  // epilogue: rescale, +b_enc, relu, emit candidates (v>=2.0) + LDS histogram.
  // tile LDS dead: hist -> AS[0], stash -> BS[0].
  u32* hist = (u32*)&AS[0][0];
  u32* s_sidx = (u32*)&BS[0][0];
  float* s_sval = (float*)&BS[0][STASH * 4];
  for (int i2 = tid; i2 < 2048; i2 += 256) hist[i2] = 0;
  __syncthreads();

  const long gm0 = m0 + wm * 64 + lh * 4;
  const long gn0 = n0 + wn * 64 + l15;
#pragma unroll
  for (int n = 0; n < 4; ++n) {
    const long col = gn0 + n * 16;
    const float be = b_enc[col];
#pragma unroll
    for (int m = 0; m < 4; ++m) {
      const long row = gm0 + m * 16;
#pragma unroll
      for (int rr = 0; rr < 4; ++rr) {
        float v = fmaxf((float)acc[m][n][rr] * INV_S + be, 0.f);
        if (v >= 2.0f) {
          u32 bin = (__float_as_uint(v) - 0x40000000u) >> 13;
          if (bin > 2047u) bin = 2047u;
          atomicAdd(&hist[bin], 1u);
          u32 flat = (u32)((row + rr) * D_ + col);
          u32 p = atomicAdd(&s_cnt, 1u);
          if (p < STASH) { s_sidx[p] = flat; s_sval[p] = v; }
          else { u32 g = atomicAdd(&meta_u[1], 1u); if (g < CAP0) { c0i[g] = flat; c0v[g] = v; } }
        }
      }
    }
  }
  __syncthreads();
  if (tid == 0) s_base = atomicAdd(&meta_u[1], s_cnt < (u32)STASH ? s_cnt : (u32)STASH);
  __syncthreads();
  const u32 c = s_cnt < (u32)STASH ? s_cnt : (u32)STASH;
  for (u32 i2 = tid; i2 < c; i2 += 256) {
    u32 g = s_base + i2;
    if (g < CAP0) { c0i[g] = s_sidx[i2]; c0v[g] = s_sval[i2]; }
  }
  for (int i2 = tid; i2 < 2048; i2 += 256) { u32 cc = hist[i2]; if (cc) atomicAdd(&ghist[i2], cc); }
}

// ---------------- fused tau + filter + exact fp32 recompute ----------------
__global__ void k_fr(const float* __restrict__ x, const float* __restrict__ W,
                     const float* __restrict__ b_enc, const float* __restrict__ b_dec,
                     const u32* __restrict__ c0i, const float* __restrict__ c0v,
                     const u32* __restrict__ ghist, u32* meta_u,
                     u32* __restrict__ cidx2, float* __restrict__ cval2) {
  __shared__ float s_tau;
  if (threadIdx.x < 64) {                  // wave 0: compute tau from ghist
    const int lane = threadIdx.x;
    u32 sum = 0;
#pragma unroll
    for (int i = 0; i < 8; ++i) {
      uint4 v = *(const uint4*)(ghist + lane * 32 + i * 4);
      sum += v.x + v.y + v.z + v.w;
    }
    u32 suf = sum;
#pragma unroll
    for (int o = 1; o < 64; o <<= 1) {
      u32 t = __shfl_down(suf, o);
      suf += (lane + o < 64) ? t : 0u;
    }
    u64 ball = __ballot(suf >= (u32)K_);
    const int cstar = ball ? (63 - __builtin_clzll(ball)) : 0;
    const u32 suf_c = __shfl(suf, cstar);
    const u32 sum_c = __shfl(sum, cstar);
    if (lane == cstar) {
      float ta;
      if (!ball) ta = 2.0f;
      else {
        u32 cum = suf_c - sum_c;
        int b = cstar * 32;
        for (int i = 31; i >= 0; --i) {
          cum += ghist[cstar * 32 + i];
          if (cum >= (u32)K_) { b = cstar * 32 + i; break; }
        }
        ta = __uint_as_float(0x40000000u + ((u32)b << 13));
      }
      s_tau = ta - MARGIN;   // margin > 2x max i8-screening error
    }
  }
  __syncthreads();
  const float tau = s_tau;

  const int lane = threadIdx.x & 63;
  const u32 wglob = blockIdx.x * 4 + (threadIdx.x >> 6);
  const u32 nw = gridDim.x * 4;
  u32 n = meta_u[1]; if (n > CAP0) n = CAP0;
  const u32 ngrp = (n + 63) >> 6;
  for (u32 g = wglob; g < ngrp; g += nw) {
    const u32 j = g * 64 + lane;
    bool pass = false; u32 myi = 0;
    if (j < n) { float v = c0v[j]; if (v >= tau) { pass = true; myi = c0i[j]; } }
    u64 m = __ballot(pass);
    while (m) {
      const int b = __ffsll((long long)m) - 1;
      m &= m - 1;
      const u32 idx = __shfl(myi, b);
      const int bb = (int)(idx >> 15);
      const int dd = (int)(idx & (D_ - 1));
      const float4* xp = (const float4*)(x + (long)bb * A_);
      const float4* wp = (const float4*)(W + (long)dd * A_);
      const float4* bp = (const float4*)b_dec;
      float sacc = 0.f;
#pragma unroll
      for (int i = 0; i < 16; ++i) {
        float4 xv = xp[i * 64 + lane], bv = bp[i * 64 + lane], wv = wp[i * 64 + lane];
        sacc += (xv.x - bv.x) * wv.x + (xv.y - bv.y) * wv.y +
                (xv.z - bv.z) * wv.z + (xv.w - bv.w) * wv.w;
      }
#pragma unroll
      for (int o = 32; o > 0; o >>= 1) sacc += __shfl_xor(sacc, o);
      if (lane == 0) {
        u32 p = atomicAdd(&meta_u[7], 1u);
        if (p < CAP) { cidx2[p] = idx; cval2[p] = fmaxf(sacc + b_enc[dd], 0.f); }
      }
    }
  }
}

// ---------------- fused select: radix K-th + tie-break + per-row CSR bucket ----------------
__global__ void __launch_bounds__(1024)
k_select(u32* meta_u, const u32* __restrict__ cidx2, const float* __restrict__ cval2,
         u32* __restrict__ row_cnt, u32* __restrict__ row_idx, float* __restrict__ row_val) {
  __shared__ u32 hist[256];
  __shared__ u32 rc[2048];
  __shared__ u32 eq[4096];
  __shared__ u32 sprefix, skrem, sneq;
  u32 n = meta_u[7]; if (n > CAP) n = CAP;
  for (int i = threadIdx.x; i < 2048; i += 1024) rc[i] = 0;
  if (threadIdx.x == 0) { sprefix = 0; skrem = K_; sneq = 0; }
  __syncthreads();
  for (int pass = 0; pass < 4; ++pass) {
    const int shift = 24 - 8 * pass;
    if (threadIdx.x < 256) hist[threadIdx.x] = 0;
    __syncthreads();
    const u32 pfx = sprefix;
    for (u32 j = threadIdx.x; j < n; j += 1024) {
      const u32 key = __float_as_uint(cval2[j]);
      if (pass == 0 || (key >> (shift + 8)) == pfx)
        atomicAdd(&hist[(key >> shift) & 255u], 1u);
    }
    __syncthreads();
    if (threadIdx.x == 0) {
      u32 cum = 0; int dg = 255;
      const u32 kr = skrem;
      for (; dg > 0; --dg) { if (cum + hist[dg] >= kr) break; cum += hist[dg]; }
      skrem = kr - cum; sprefix = (pfx << 8) | (u32)dg;
    }
    __syncthreads();
  }
  const u32 tkey = sprefix;
  for (u32 j = threadIdx.x; j < n; j += 1024) {
    const u32 key = __float_as_uint(cval2[j]);
    if (key > tkey) {
      const u32 idx = cidx2[j];
      const u32 row = idx >> 15;
      u32 p = atomicAdd(&rc[row], 1u);
      if (p < (u32)ROWCAP) {
        row_idx[row * ROWCAP + p] = idx & (D_ - 1);
        row_val[row * ROWCAP + p] = cval2[j];
      }
    } else if (key == tkey) {
      u32 p = atomicAdd(&sneq, 1u);
      if (p < 4096u) eq[p] = cidx2[j];
    }
  }
  __syncthreads();
  if (threadIdx.x == 0) {
    const u32 need = skrem;
    u32 neq = sneq; if (neq > 4096u) neq = 4096u;
    const float tv = __uint_as_float(tkey);
    u32 last = 0; bool first = true;
    for (u32 rr = 0; rr < need; ++rr) {
      u32 best = 0xFFFFFFFFu;
      for (u32 i = 0; i < neq; ++i) {
        const u32 v = eq[i];
        if ((first || v > last) && v < best) best = v;
      }
      if (best != 0xFFFFFFFFu) {
        const u32 row = best >> 15;
        u32 p = rc[row]++;
        if (p < (u32)ROWCAP) {
          row_idx[row * ROWCAP + p] = best & (D_ - 1);
          row_val[row * ROWCAP + p] = tv;
        }
      }
      last = best; first = false;
    }
  }
  __syncthreads();
  for (int i = threadIdx.x; i < 2048; i += 1024) {
    u32 c = rc[i]; row_cnt[i] = c < (u32)ROWCAP ? c : (u32)ROWCAP;
  }
}

// ---------------- decode: one block per output row, register accumulate, plain stores ----------------
__global__ void k_decode(const u32* __restrict__ row_cnt, const u32* __restrict__ row_idx,
                         const float* __restrict__ row_val, const float* __restrict__ Wd,
                         const float* __restrict__ b_dec, float* __restrict__ out) {
  const int row = blockIdx.x;
  const int t = threadIdx.x;
  float4 a[4];
#pragma unroll
  for (int c = 0; c < 4; ++c) a[c] = *(const float4*)(b_dec + (t + c * 256) * 4);
  const u32 cnt = row_cnt[row];
  for (u32 i = 0; i < cnt; ++i) {
    const u32 dd = row_idx[row * ROWCAP + i];
    const float act = row_val[row * ROWCAP + i];
    const float4* wp = (const float4*)(Wd + (long)dd * A_);
#pragma unroll
    for (int c = 0; c < 4; ++c) {
      float4 wv = wp[t + c * 256];
      a[c].x += act * wv.x; a[c].y += act * wv.y;
      a[c].z += act * wv.z; a[c].w += act * wv.w;
    }
  }
  float* op = out + (long)row * A_;
#pragma unroll
  for (int c = 0; c < 4; ++c) *(float4*)(op + (t + c * 256) * 4) = a[c];
}

extern "C" void kernel_launch(void* const* d_in, const int* in_sizes, int n_in,
                              void* d_out, int out_size, void* d_ws, size_t ws_size,
                              hipStream_t stream) {
  const float* x     = (const float*)d_in[0];
  const float* W_enc = (const float*)d_in[1];
  const float* b_enc = (const float*)d_in[2];
  const float* W_dec = (const float*)d_in[3];
  const float* b_dec = (const float*)d_in[4];
  float* out = (float*)d_out;
  char* w = (char*)d_ws;

  const long off_Xq   = 0L;                         // 8,388,608
  const long off_Wq   = 8388608L;                   // +134,217,728
  const long off_c0i  = off_Wq + 134217728L;        // 142,606,336
  const long off_c0v  = off_c0i + 16777216L;        // 159,383,552
  const long off_hist = off_c0v + 16777216L;        // 176,160,768 (ghist 8192 + meta 256)
  const long off_meta = off_hist + 8192L;
  const long off_ci2  = off_meta + 256L;
  const long off_cv2  = off_ci2 + 524288L;
  const long off_rcnt = off_cv2 + 524288L;
  const long off_ridx = off_rcnt + 8192L;
  const long off_rval = off_ridx + 524288L;
  const long need_ws  = off_rval + 524288L;         // ~170 MiB
  if ((long)ws_size < need_ws) return;              // cannot run safely

  char* Xq     = (char*)(w + off_Xq);
  char* Wq     = (char*)(w + off_Wq);
  u32* c0i     = (u32*)(w + off_c0i);
  float* c0v   = (float*)(w + off_c0v);
  u32* ghist   = (u32*)(w + off_hist);
  u32* meta_u  = (u32*)(w + off_meta);
  u32* cidx2   = (u32*)(w + off_ci2);
  float* cval2 = (float*)(w + off_cv2);
  u32* row_cnt = (u32*)(w + off_rcnt);
  u32* row_idx = (u32*)(w + off_ridx);
  float* row_val = (float*)(w + off_rval);

  k_prep<<<34817, 256, 0, stream>>>(W_enc, Wq, x, b_dec, Xq, ghist);
  k_gemm<<<4096, 256, 0, stream>>>(Xq, Wq, b_enc, meta_u, ghist, c0i, c0v);
  k_fr<<<2048, 256, 0, stream>>>(x, W_enc, b_enc, b_dec, c0i, c0v, ghist, meta_u, cidx2, cval2);
  k_select<<<1, 1024, 0, stream>>>(meta_u, cidx2, cval2, row_cnt, row_idx, row_val);
  k_decode<<<B_, 256, 0, stream>>>(row_cnt, row_idx, row_val, W_dec, b_dec, out);
}

// Round 13
// 674.290 us; speedup vs baseline: 1.0956x; 1.0956x over previous
//
#include <hip/hip_runtime.h>

typedef unsigned int u32;
typedef unsigned short u16;
typedef unsigned long long u64;

#define B_ 2048
#define A_ 4096
#define D_ 32768
#define K_ 4096
#define CAP0 4194304   // raw candidates (v >= 2.0), expect ~1.5M
#define CAP  131072    // filtered candidates (v >= tau), expect ~12K
#define STASH 2048
#define S_X 28.0f
#define S_W 1792.0f
#define INV_S (1.0f / (28.0f * 1792.0f))
#define MARGIN 0.28f
#define ROWCAP 64

using f32x4 = __attribute__((ext_vector_type(4))) float;
using i32x4 = __attribute__((ext_vector_type(4))) int;

typedef const u32 __attribute__((address_space(1)))* gas_ptr;
typedef u32 __attribute__((address_space(3)))* las_ptr;

__device__ __forceinline__ void load16(const void* g, void* l) {
  __builtin_amdgcn_global_load_lds((gas_ptr)g, (las_ptr)l, 16, 0, 0);
}

__device__ __forceinline__ u32 q8x4(float4 v, float s) {
  int q0 = __float2int_rn(v.x * s); q0 = q0 < -127 ? -127 : (q0 > 127 ? 127 : q0);
  int q1 = __float2int_rn(v.y * s); q1 = q1 < -127 ? -127 : (q1 > 127 ? 127 : q1);
  int q2 = __float2int_rn(v.z * s); q2 = q2 < -127 ? -127 : (q2 > 127 ? 127 : q2);
  int q3 = __float2int_rn(v.w * s); q3 = q3 < -127 ? -127 : (q3 > 127 ? 127 : q3);
  return (u32)(q0 & 0xff) | ((u32)(q1 & 0xff) << 8) | ((u32)(q2 & 0xff) << 16) | ((u32)(q3 & 0xff) << 24);
}

// ---------------- fused prep: quantize W, quantize x-b_dec, zero hist/meta ----------------
__global__ void k_prep(const float* __restrict__ Wf, char* __restrict__ Wq,
                       const float* __restrict__ x, const float* __restrict__ b_dec,
                       char* __restrict__ Xq, u32* __restrict__ gzero) {
  const int bid = blockIdx.x;
  const int t = threadIdx.x;
  if (bid < 32768) {                       // W_enc -> i8 (134.2M elems; block = 4096 elems)
    const long eb = (long)bid * 4096;
#pragma unroll
    for (int p = 0; p < 4; ++p) {
      const long e = eb + p * 1024 + t * 4;
      float4 v = *(const float4*)(Wf + e);
      *(u32*)(Wq + e) = q8x4(v, S_W);
    }
  } else if (bid < 34816) {                // (x - b_dec) -> i8 (8.39M elems)
    const long eb = (long)(bid - 32768) * 4096;
#pragma unroll
    for (int p = 0; p < 4; ++p) {
      const long e = eb + p * 1024 + t * 4;
      const int a0 = (int)(e & (A_ - 1));
      float4 xv = *(const float4*)(x + e);
      float4 bv = *(const float4*)(b_dec + a0);
      float4 d; d.x = xv.x - bv.x; d.y = xv.y - bv.y; d.z = xv.z - bv.z; d.w = xv.w - bv.w;
      *(u32*)(Xq + e) = q8x4(d, S_X);
    }
  } else {                                 // zero ghist(2048) + meta(64) words
    for (int i = t; i < 2112; i += 256) gzero[i] = 0;
  }
}

// ---------------- i8 screening GEMM: 256x256, BK=128, 8 waves, 4-phase/tile schedule.
// R10 champion: deep read-pipeline (next tile's 16-read group issued in P4 post-MFMA),
// staging advanced to P1/P2 so vmcnt(8)@P2-close proves tile t+1 resident. ----------------

#define PH_OPEN_LG4 \
  __builtin_amdgcn_sched_barrier(0); \
  __builtin_amdgcn_s_barrier(); \
  asm volatile("s_waitcnt lgkmcnt(4)" ::: "memory"); \
  __builtin_amdgcn_sched_barrier(0);

#define PH_OPEN_LG0 \
  __builtin_amdgcn_sched_barrier(0); \
  __builtin_amdgcn_s_barrier(); \
  asm volatile("s_waitcnt lgkmcnt(0)" ::: "memory"); \
  __builtin_amdgcn_sched_barrier(0);

#define PH_OPEN_NB \
  __builtin_amdgcn_sched_barrier(0); \
  __builtin_amdgcn_s_barrier(); \
  __builtin_amdgcn_sched_barrier(0);

#define PH_CLOSE \
  __builtin_amdgcn_sched_barrier(0); \
  __builtin_amdgcn_s_barrier();

#define PH_CLOSE_VM(N) \
  __builtin_amdgcn_sched_barrier(0); \
  asm volatile("s_waitcnt vmcnt(" #N ")" ::: "memory"); \
  __builtin_amdgcn_s_barrier();

#define MFMAQ(MB, NB) \
  __builtin_amdgcn_s_setprio(1); \
  { \
    _Pragma("unroll") \
    for (int m = 0; m < 4; ++m) { \
      _Pragma("unroll") \
      for (int n = 0; n < 2; ++n) { \
        acc[MB + m][NB + n] = __builtin_amdgcn_mfma_i32_16x16x64_i8(a[m][0], b[NB + n][0], acc[MB + m][NB + n], 0, 0, 0); \
        acc[MB + m][NB + n] = __builtin_amdgcn_mfma_i32_16x16x64_i8(a[m][1], b[NB + n][1], acc[MB + m][NB + n], 0, 0, 0); \
      } \
    } \
  } \
  __builtin_amdgcn_s_setprio(0);

__global__ void __launch_bounds__(512, 1)
k_gemm(const char* __restrict__ Xq, const char* __restrict__ Wq,
       const float* __restrict__ b_enc,
       u32* meta_u, u32* __restrict__ ghist,
       u32* __restrict__ c0i, float* __restrict__ c0v) {
  __shared__ __align__(16) char AS[2][256 * 128];   // 64 KiB
  __shared__ __align__(16) char BS[2][256 * 128];   // 64 KiB
  __shared__ u32 s_cnt, s_base;
  const int tid = threadIdx.x;
  const int lane = tid & 63, wid = tid >> 6;
  const int wm = wid >> 2, wn = wid & 3;            // 2M x 4N waves, 128x64 out each

  // XCD-aware bijective swizzle: 1024 blocks -> 128-block chunks per XCD, bm fastest
  const int bid = blockIdx.x;
  const int virt = (bid & 7) * 128 + (bid >> 3);
  const int bm = virt & 7, bn = virt >> 3;
  const long m0 = (long)bm * 256, n0 = (long)bn * 256;

  if (tid == 0) s_cnt = 0;

  // staging: per half-tile (128 rows x 128 B), 2 x load16/thread.
  const int srow = tid >> 3;
  const int sslot = (tid & 7) ^ (srow & 7);
  const char* Abase = Xq + (m0 + srow) * (long)A_ + sslot * 16;
  const char* Bbase = Wq + (n0 + srow) * (long)A_ + sslot * 16;

  auto stageA = [&](int h, int kt) {                // h: row-half (0/1)
    char* dst = &AS[kt & 1][h * 16384] + tid * 16;
    const char* src = Abase + (long)(h * 128) * A_ + kt * 128;
    load16(src, dst);
    load16(src + 64L * A_, dst + 8192);
  };
  auto stageB = [&](int h, int kt) {
    char* dst = &BS[kt & 1][h * 16384] + tid * 16;
    const char* src = Bbase + (long)(h * 128) * A_ + kt * 128;
    load16(src, dst);
    load16(src + 64L * A_, dst + 8192);
  };

  // fragment reads: row R, kslice ks -> byte = R*128 + (((ks<<2)|lh) ^ (l15&7))*16
  const int l15 = lane & 15, lh = lane >> 4;
  const int r7 = l15 & 7;
  const int sK0 = (lh ^ r7) * 16;
  const int sK1 = ((4 | lh) ^ r7) * 16;
  const int aBase = (wm * 128 + l15) * 128;
  const int bBase = (wn * 64 + l15) * 128;

  i32x4 acc[8][4] = {};
  i32x4 a[4][2], b[4][2];

  auto ldA4 = [&](int buf, int mb) {
#pragma unroll
    for (int m = 0; m < 4; ++m) {
      a[m][0] = *(const i32x4*)&AS[buf][aBase + (mb + m) * 2048 + sK0];
      a[m][1] = *(const i32x4*)&AS[buf][aBase + (mb + m) * 2048 + sK1];
    }
  };
  auto ldB4 = [&](int buf) {
#pragma unroll
    for (int n = 0; n < 4; ++n) {
      b[n][0] = *(const i32x4*)&BS[buf][bBase + n * 2048 + sK0];
      b[n][1] = *(const i32x4*)&BS[buf][bBase + n * 2048 + sK1];
    }
  };

  // prologue: fully stage tiles 0 and 1 (16 loads); tile0 resident after vmcnt(8)
  stageB(0, 0); stageB(1, 0); stageA(0, 0); stageA(1, 0);
  stageB(0, 1); stageB(1, 1); stageA(0, 1); stageA(1, 1);
  asm volatile("s_waitcnt vmcnt(8)" ::: "memory");
  __builtin_amdgcn_s_barrier();
  ldA4(0, 0); ldB4(0);                     // group for t=0 P1 (a-lo + b, 16 reads)

#pragma unroll 1
  for (int t = 0; t < 32; ++t) {
    const int buf = t & 1;
    // ---- P1: a-lo x b01 (group pre-issued; first 12 reads needed) ----
    PH_OPEN_LG4;
    MFMAQ(0, 0);
    if (t < 30) { stageB(0, t + 2); stageB(1, t + 2); }  // B(t): reads issued prev P4
    PH_CLOSE;
    // ---- P2: a-lo x b23 (b23 had a full phase) ----
    PH_OPEN_LG0;
    MFMAQ(0, 2);
    ldA4(buf, 4);                                        // a-hi reload (post-MFMA, WAR-safe)
    if (t < 30) { stageA(0, t + 2); stageA(1, t + 2); }  // A(t): reads issued this phase
    PH_CLOSE_VM(8);                                      // tile t+1 fully resident from here
    // ---- P3: a-hi x b01 ----
    PH_OPEN_LG0;
    MFMAQ(4, 0);
    PH_CLOSE;
    // ---- P4: a-hi x b23; issue next tile's group under this MFMA's shadow ----
    PH_OPEN_NB;
    MFMAQ(4, 2);
    if (t < 31) { ldA4(buf ^ 1, 0); ldB4(buf ^ 1); }
    PH_CLOSE;
  }
  __syncthreads();

  // epilogue: rescale, +b_enc, relu, emit candidates (v>=2.0) + LDS histogram.
  // All tile LDS dead: hist -> AS[0], stash -> BS[0].
  u32* hist = (u32*)&AS[0][0];
  u32* s_sidx = (u32*)&BS[0][0];
  float* s_sval = (float*)&BS[0][STASH * 4];
  for (int i2 = tid; i2 < 2048; i2 += 512) hist[i2] = 0;
  __syncthreads();

  const long gm0 = m0 + wm * 128 + lh * 4;
  const long gn0 = n0 + wn * 64 + l15;
#pragma unroll
  for (int n = 0; n < 4; ++n) {
    const long col = gn0 + n * 16;
    const float be = b_enc[col];
#pragma unroll
    for (int m = 0; m < 8; ++m) {
      const long row = gm0 + m * 16;
#pragma unroll
      for (int rr = 0; rr < 4; ++rr) {
        float v = fmaxf((float)acc[m][n][rr] * INV_S + be, 0.f);
        if (v >= 2.0f) {
          u32 bin = (__float_as_uint(v) - 0x40000000u) >> 13;
          if (bin > 2047u) bin = 2047u;
          atomicAdd(&hist[bin], 1u);
          u32 flat = (u32)((row + rr) * D_ + col);
          u32 p = atomicAdd(&s_cnt, 1u);
          if (p < STASH) { s_sidx[p] = flat; s_sval[p] = v; }
          else { u32 g = atomicAdd(&meta_u[1], 1u); if (g < CAP0) { c0i[g] = flat; c0v[g] = v; } }
        }
      }
    }
  }
  __syncthreads();
  if (tid == 0) s_base = atomicAdd(&meta_u[1], s_cnt < (u32)STASH ? s_cnt : (u32)STASH);
  __syncthreads();
  const u32 c = s_cnt < (u32)STASH ? s_cnt : (u32)STASH;
  for (u32 i2 = tid; i2 < c; i2 += 512) {
    u32 g = s_base + i2;
    if (g < CAP0) { c0i[g] = s_sidx[i2]; c0v[g] = s_sval[i2]; }
  }
  for (int i2 = tid; i2 < 2048; i2 += 512) { u32 cc = hist[i2]; if (cc) atomicAdd(&ghist[i2], cc); }
}

// ---------------- fused tau + filter + exact fp32 recompute ----------------
__global__ void k_fr(const float* __restrict__ x, const float* __restrict__ W,
                     const float* __restrict__ b_enc, const float* __restrict__ b_dec,
                     const u32* __restrict__ c0i, const float* __restrict__ c0v,
                     const u32* __restrict__ ghist, u32* meta_u,
                     u32* __restrict__ cidx2, float* __restrict__ cval2) {
  __shared__ float s_tau;
  if (threadIdx.x < 64) {                  // wave 0: compute tau from ghist
    const int lane = threadIdx.x;
    u32 sum = 0;
#pragma unroll
    for (int i = 0; i < 8; ++i) {
      uint4 v = *(const uint4*)(ghist + lane * 32 + i * 4);
      sum += v.x + v.y + v.z + v.w;
    }
    u32 suf = sum;
#pragma unroll
    for (int o = 1; o < 64; o <<= 1) {
      u32 t = __shfl_down(suf, o);
      suf += (lane + o < 64) ? t : 0u;
    }
    u64 ball = __ballot(suf >= (u32)K_);
    const int cstar = ball ? (63 - __builtin_clzll(ball)) : 0;
    const u32 suf_c = __shfl(suf, cstar);
    const u32 sum_c = __shfl(sum, cstar);
    if (lane == cstar) {
      float ta;
      if (!ball) ta = 2.0f;
      else {
        u32 cum = suf_c - sum_c;
        int b = cstar * 32;
        for (int i = 31; i >= 0; --i) {
          cum += ghist[cstar * 32 + i];
          if (cum >= (u32)K_) { b = cstar * 32 + i; break; }
        }
        ta = __uint_as_float(0x40000000u + ((u32)b << 13));
      }
      s_tau = ta - MARGIN;   // margin > 2x max i8-screening error
    }
  }
  __syncthreads();
  const float tau = s_tau;

  const int lane = threadIdx.x & 63;
  const u32 wglob = blockIdx.x * 4 + (threadIdx.x >> 6);
  const u32 nw = gridDim.x * 4;
  u32 n = meta_u[1]; if (n > CAP0) n = CAP0;
  const u32 ngrp = (n + 63) >> 6;
  for (u32 g = wglob; g < ngrp; g += nw) {
    const u32 j = g * 64 + lane;
    bool pass = false; u32 myi = 0;
    if (j < n) { float v = c0v[j]; if (v >= tau) { pass = true; myi = c0i[j]; } }
    u64 m = __ballot(pass);
    while (m) {
      const int b = __ffsll((long long)m) - 1;
      m &= m - 1;
      const u32 idx = __shfl(myi, b);
      const int bb = (int)(idx >> 15);
      const int dd = (int)(idx & (D_ - 1));
      const float4* xp = (const float4*)(x + (long)bb * A_);
      const float4* wp = (const float4*)(W + (long)dd * A_);
      const float4* bp = (const float4*)b_dec;
      float sacc = 0.f;
#pragma unroll
      for (int i = 0; i < 16; ++i) {
        float4 xv = xp[i * 64 + lane], bv = bp[i * 64 + lane], wv = wp[i * 64 + lane];
        sacc += (xv.x - bv.x) * wv.x + (xv.y - bv.y) * wv.y +
                (xv.z - bv.z) * wv.z + (xv.w - bv.w) * wv.w;
      }
#pragma unroll
      for (int o = 32; o > 0; o >>= 1) sacc += __shfl_xor(sacc, o);
      if (lane == 0) {
        u32 p = atomicAdd(&meta_u[7], 1u);
        if (p < CAP) { cidx2[p] = idx; cval2[p] = fmaxf(sacc + b_enc[dd], 0.f); }
      }
    }
  }
}

// ---------------- fused select: radix K-th + tie-break + per-row CSR bucket ----------------
__global__ void __launch_bounds__(1024)
k_select(u32* meta_u, const u32* __restrict__ cidx2, const float* __restrict__ cval2,
         u32* __restrict__ row_cnt, u32* __restrict__ row_idx, float* __restrict__ row_val) {
  __shared__ u32 hist[256];
  __shared__ u32 rc[2048];
  __shared__ u32 eq[4096];
  __shared__ u32 sprefix, skrem, sneq;
  u32 n = meta_u[7]; if (n > CAP) n = CAP;
  for (int i = threadIdx.x; i < 2048; i += 1024) rc[i] = 0;
  if (threadIdx.x == 0) { sprefix = 0; skrem = K_; sneq = 0; }
  __syncthreads();
  for (int pass = 0; pass < 4; ++pass) {
    const int shift = 24 - 8 * pass;
    if (threadIdx.x < 256) hist[threadIdx.x] = 0;
    __syncthreads();
    const u32 pfx = sprefix;
    for (u32 j = threadIdx.x; j < n; j += 1024) {
      const u32 key = __float_as_uint(cval2[j]);
      if (pass == 0 || (key >> (shift + 8)) == pfx)
        atomicAdd(&hist[(key >> shift) & 255u], 1u);
    }
    __syncthreads();
    if (threadIdx.x == 0) {
      u32 cum = 0; int dg = 255;
      const u32 kr = skrem;
      for (; dg > 0; --dg) { if (cum + hist[dg] >= kr) break; cum += hist[dg]; }
      skrem = kr - cum; sprefix = (pfx << 8) | (u32)dg;
    }
    __syncthreads();
  }
  const u32 tkey = sprefix;
  for (u32 j = threadIdx.x; j < n; j += 1024) {
    const u32 key = __float_as_uint(cval2[j]);
    if (key > tkey) {
      const u32 idx = cidx2[j];
      const u32 row = idx >> 15;
      u32 p = atomicAdd(&rc[row], 1u);
      if (p < (u32)ROWCAP) {
        row_idx[row * ROWCAP + p] = idx & (D_ - 1);
        row_val[row * ROWCAP + p] = cval2[j];
      }
    } else if (key == tkey) {
      u32 p = atomicAdd(&sneq, 1u);
      if (p < 4096u) eq[p] = cidx2[j];
    }
  }
  __syncthreads();
  if (threadIdx.x == 0) {
    const u32 need = skrem;
    u32 neq = sneq; if (neq > 4096u) neq = 4096u;
    const float tv = __uint_as_float(tkey);
    u32 last = 0; bool first = true;
    for (u32 rr = 0; rr < need; ++rr) {
      u32 best = 0xFFFFFFFFu;
      for (u32 i = 0; i < neq; ++i) {
        const u32 v = eq[i];
        if ((first || v > last) && v < best) best = v;
      }
      if (best != 0xFFFFFFFFu) {
        const u32 row = best >> 15;
        u32 p = rc[row]++;
        if (p < (u32)ROWCAP) {
          row_idx[row * ROWCAP + p] = best & (D_ - 1);
          row_val[row * ROWCAP + p] = tv;
        }
      }
      last = best; first = false;
    }
  }
  __syncthreads();
  for (int i = threadIdx.x; i < 2048; i += 1024) {
    u32 c = rc[i]; row_cnt[i] = c < (u32)ROWCAP ? c : (u32)ROWCAP;
  }
}

// ---------------- decode: one block per output row, register accumulate, plain stores ----------------
__global__ void k_decode(const u32* __restrict__ row_cnt, const u32* __restrict__ row_idx,
                         const float* __restrict__ row_val, const float* __restrict__ Wd,
                         const float* __restrict__ b_dec, float* __restrict__ out) {
  const int row = blockIdx.x;
  const int t = threadIdx.x;
  float4 a[4];
#pragma unroll
  for (int c = 0; c < 4; ++c) a[c] = *(const float4*)(b_dec + (t + c * 256) * 4);
  const u32 cnt = row_cnt[row];
  for (u32 i = 0; i < cnt; ++i) {
    const u32 dd = row_idx[row * ROWCAP + i];
    const float act = row_val[row * ROWCAP + i];
    const float4* wp = (const float4*)(Wd + (long)dd * A_);
#pragma unroll
    for (int c = 0; c < 4; ++c) {
      float4 wv = wp[t + c * 256];
      a[c].x += act * wv.x; a[c].y += act * wv.y;
      a[c].z += act * wv.z; a[c].w += act * wv.w;
    }
  }
  float* op = out + (long)row * A_;
#pragma unroll
  for (int c = 0; c < 4; ++c) *(float4*)(op + (t + c * 256) * 4) = a[c];
}

extern "C" void kernel_launch(void* const* d_in, const int* in_sizes, int n_in,
                              void* d_out, int out_size, void* d_ws, size_t ws_size,
                              hipStream_t stream) {
  const float* x     = (const float*)d_in[0];
  const float* W_enc = (const float*)d_in[1];
  const float* b_enc = (const float*)d_in[2];
  const float* W_dec = (const float*)d_in[3];
  const float* b_dec = (const float*)d_in[4];
  float* out = (float*)d_out;
  char* w = (char*)d_ws;

  const long off_Xq   = 0L;                         // 8,388,608
  const long off_Wq   = 8388608L;                   // +134,217,728
  const long off_c0i  = off_Wq + 134217728L;        // 142,606,336
  const long off_c0v  = off_c0i + 16777216L;        // 159,383,552
  const long off_hist = off_c0v + 16777216L;        // 176,160,768 (ghist 8192 + meta 256)
  const long off_meta = off_hist + 8192L;
  const long off_ci2  = off_meta + 256L;
  const long off_cv2  = off_ci2 + 524288L;
  const long off_rcnt = off_cv2 + 524288L;
  const long off_ridx = off_rcnt + 8192L;
  const long off_rval = off_ridx + 524288L;
  const long need_ws  = off_rval + 524288L;         // ~170 MiB
  if ((long)ws_size < need_ws) return;              // cannot run safely

  char* Xq     = (char*)(w + off_Xq);
  char* Wq     = (char*)(w + off_Wq);
  u32* c0i     = (u32*)(w + off_c0i);
  float* c0v   = (float*)(w + off_c0v);
  u32* ghist   = (u32*)(w + off_hist);
  u32* meta_u  = (u32*)(w + off_meta);
  u32* cidx2   = (u32*)(w + off_ci2);
  float* cval2 = (float*)(w + off_cv2);
  u32* row_cnt = (u32*)(w + off_rcnt);
  u32* row_idx = (u32*)(w + off_ridx);
  float* row_val = (float*)(w + off_rval);

  k_prep<<<34817, 256, 0, stream>>>(W_enc, Wq, x, b_dec, Xq, ghist);
  k_gemm<<<1024, 512, 0, stream>>>(Xq, Wq, b_enc, meta_u, ghist, c0i, c0v);
  k_fr<<<2048, 256, 0, stream>>>(x, W_enc, b_enc, b_dec, c0i, c0v, ghist, meta_u, cidx2, cval2);
  k_select<<<1, 1024, 0, stream>>>(meta_u, cidx2, cval2, row_cnt, row_idx, row_val);
  k_decode<<<B_, 256, 0, stream>>>(row_cnt, row_idx, row_val, W_dec, b_dec, out);
}